// Round 1
// baseline (303.781 us; speedup 1.0000x reference)
//
#include <hip/hip_runtime.h>

// DarkChannel: cmin over C=3, then 15x15 min erosion, +inf border.
// Round 6: traffic + LDS-conflict restructure.
//  - TY 16->32: staging read amplification (ROWS*BW)/(TY*TX) 1.99x -> 1.53x
//    (saves ~93 MB of HBM reads). LDS 50.0 KB -> 3 blocks/CU (12 waves/CU).
//  - horizontal pass reads 5x float4 (b128, data-limited) instead of
//    10x float2 (b64 at inherent 8-way bank conflict: 64 lanes at 16B
//    stride inside one row alias to 8 bank-groups). Same bytes, ~4x less
//    serialized LDS time in this phase, fewer fminf.
//  - 1D grid + bijective XCD-chunked swizzle (2048 blocks = 8*256):
//    each XCD works 2 whole batch images; y-adjacent tiles (sharing a
//    14-row x 1088B halo band) co-reside on one XCD's L2.

#define IMG_H 1024
#define IMG_W 1024
#define IMG_C 3
#define IMG_B 16
#define TY    32              // output rows per block
#define TX    256             // output cols per block
#define HALO  8
#define BW    (TX + 2*HALO)   // 272 staged cols
#define ROWS  (TY + 14)       // 46 staged rows
#define NCH   (BW / 4)        // 68 float4 chunks per staged row
#define NT    256
#define RAD   7
#define NTASK (ROWS * NCH)    // 3128 staging tasks

__device__ __forceinline__ float4 min4(float4 a, float4 b) {
    return make_float4(fminf(a.x, b.x), fminf(a.y, b.y),
                       fminf(a.z, b.z), fminf(a.w, b.w));
}

__global__ __launch_bounds__(NT, 3)
void DarkChannel_77713138254515_kernel(const float* __restrict__ img,
                                       float* __restrict__ out) {
    __shared__ float buf[ROWS][BW];          // 46*272*4 = 50048 B -> 3 blk/CU

    const int t = threadIdx.x;

    // ---- bijective XCD-chunked swizzle: nwg = 2048 = 8 XCDs * 256 ----
    // hw block bid (round-robin bid%8 across XCDs) -> logical tile swz so
    // each XCD owns a contiguous range of 256 tiles (= 2 full batch images,
    // x-fastest then y: vertical halo neighbors are 4 apart in time).
    const int bid = blockIdx.x;
    const int swz = ((bid & 7) << 8) | (bid >> 3);
    const int x0 = (swz & 3) * TX;           // 4 x-tiles
    const int y0 = ((swz >> 2) & 31) * TY;   // 32 y-tiles
    const int b  = swz >> 7;                 // 16 batches

    const size_t plane = (size_t)IMG_H * IMG_W;
    const float* imgb = img + (size_t)b * IMG_C * plane;
    float* outb = out + (size_t)b * plane;
    const float INF = __builtin_inff();
    const float4 INF4 = make_float4(INF, INF, INF, INF);

    // ---- stage: 46 rows x 68 float4 chunks = 3128 independent tasks ----
#pragma unroll
    for (int k = 0; k < 13; ++k) {
        int task = t + NT * k;
        if (task < NTASK) {
            int r  = task / NCH;             // constant div -> magic mul
            int ch = task - r * NCH;
            int y  = y0 - RAD + r;
            int gx = x0 - HALO + 4 * ch;     // 4-aligned
            bool ok = ((unsigned)y < IMG_H) & ((unsigned)gx <= IMG_W - 4);
            int yc  = min(max(y, 0), IMG_H - 1);
            int gxc = min(max(gx, 0), IMG_W - 4);
            const float* p0 = imgb + (size_t)yc * IMG_W + gxc;
            float4 v0 = *(const float4*)(p0);
            float4 v1 = *(const float4*)(p0 + plane);
            float4 v2 = *(const float4*)(p0 + 2 * plane);
            float4 v  = min4(v0, min4(v1, v2));
            if (!ok) v = INF4;
            *(float4*)&buf[r][4 * ch] = v;   // b128 writes: data-limited
        }
    }
    __syncthreads();

    // ---- vertical: van Herk per column, in place ----
    // stride-1 b32 across lanes: 2-way aliasing only (free).
    // outputs i=0..31: out[i] = min(col[i .. i+14]); col has 46 rows.
    for (int c = t; c < BW; c += NT) {       // col t, and 256+t for t<16
        float col[ROWS];
#pragma unroll
        for (int r = 0; r < ROWS; ++r) col[r] = buf[r][c];

        // segment A: outputs 0..14 (suffix over col[0..14], prefix col[15..29])
        float S[15];
        S[14] = col[14];
#pragma unroll
        for (int i = 13; i >= 0; --i) S[i] = fminf(col[i], S[i + 1]);
        buf[0][c] = S[0];
        float p = col[15];
#pragma unroll
        for (int i = 1; i < 15; ++i) {
            buf[i][c] = fminf(S[i], p);
            p = fminf(p, col[15 + i]);
        }
        // p == min(col[15..29]) (not stored directly; S1[0] equals it)

        // segment B: outputs 15..29 (suffix col[15..29], prefix col[30..44])
        float S1[15];
        S1[14] = col[29];
#pragma unroll
        for (int i = 13; i >= 0; --i) S1[i] = fminf(col[15 + i], S1[i + 1]);
        buf[15][c] = S1[0];
        float q = col[30];
#pragma unroll
        for (int i = 1; i < 15; ++i) {
            buf[15 + i][c] = fminf(S1[i], q);
            q = fminf(q, col[30 + i]);
        }
        // q == min(col[30..44])

        // segment C: outputs 30..31
        buf[30][c] = q;                      // min(col[30..44])
        float s = col[45];
#pragma unroll
        for (int i = 44; i >= 31; --i) s = fminf(s, col[i]);
        buf[31][c] = s;                      // min(col[31..45])
    }
    __syncthreads();

    // ---- horizontal: 32 rows x 64 chunks = 2048 tasks, 8/thread ----
    // 5x b128 per task (covers row[0..19] exactly) -- data-limited LDS reads.
#pragma unroll
    for (int k = 0; k < 8; ++k) {
        int task = t + NT * k;
        int r  = task >> 6;
        int ch = task & 63;
        const float* row = &buf[r][4 * ch];  // buf col 4ch <-> img col x0-8+4ch
        float4 Q[5];
#pragma unroll
        for (int j = 0; j < 5; ++j) Q[j] = *(const float4*)(row + 4 * j);
        float4 m4 = min4(Q[1], min4(Q[2], Q[3]));        // w[4..15]
        float core = fminf(fminf(m4.x, m4.y), fminf(m4.z, m4.w));
        float4 o;
        o.x = fminf(core, fminf(Q[0].y, fminf(Q[0].z, Q[0].w))); // w[1..15]
        o.y = fminf(core, fminf(Q[0].z, fminf(Q[0].w, Q[4].x))); // w[2..16]
        o.z = fminf(core, fminf(Q[0].w, fminf(Q[4].x, Q[4].y))); // w[3..17]
        o.w = fminf(core, fminf(Q[4].x, fminf(Q[4].y, Q[4].z))); // w[4..18]
        *(float4*)(outb + (size_t)(y0 + r) * IMG_W + x0 + 4 * ch) = o;
    }
}

extern "C" void kernel_launch(void* const* d_in, const int* in_sizes, int n_in,
                              void* d_out, int out_size, void* d_ws, size_t ws_size,
                              hipStream_t stream) {
    const float* img = (const float*)d_in[0];
    float* out = (float*)d_out;

    // 4 x-tiles * 32 y-tiles * 16 batches = 2048 blocks (1D for swizzle)
    DarkChannel_77713138254515_kernel<<<dim3(2048), dim3(NT), 0, stream>>>(img, out);
}